// Round 4
// baseline (93.644 us; speedup 1.0000x reference)
//
#include <hip/hip_runtime.h>
#include <hip/hip_bf16.h>
#include <stdint.h>

#define N 8192
#define K 64

typedef __attribute__((ext_vector_type(8))) __bf16 bf16x8;
typedef __attribute__((ext_vector_type(4))) float f32x4;
typedef __attribute__((address_space(3))) uint8_t lds_u8;
typedef __attribute__((address_space(1))) const uint8_t glob_u8;

// ws layout:
//   [0, 16KB)           : P1 term1 per-block partials (4096 f32)
//   [0x10000, +1MB)     : P2 term2 per-block partial G (64 * 4096 f32)
//   [0x120000, +256B)   : R1 stage2 partials (64 f32)
//   [0x120400, +256B)   : R2 stage2 partials (64 f32)

static __device__ __forceinline__ uint32_t f2bf(float f) {
  uint32_t x = __float_as_uint(f);
  return (x + 0x7FFFu + ((x >> 16) & 1u)) >> 16;  // RNE f32->bf16
}

static __device__ __forceinline__ bf16x8 pack8(float4 a, float4 b) {
  union {
    ushort u[8];
    bf16x8 v;
  } r;
  r.u[0] = (ushort)f2bf(a.x);
  r.u[1] = (ushort)f2bf(a.y);
  r.u[2] = (ushort)f2bf(a.z);
  r.u[3] = (ushort)f2bf(a.w);
  r.u[4] = (ushort)f2bf(b.x);
  r.u[5] = (ushort)f2bf(b.y);
  r.u[6] = (ushort)f2bf(b.z);
  r.u[7] = (ushort)f2bf(b.w);
  return r.v;
}

// Fused kernel, 4160 blocks:
//  blocks 0..63    : term2 — partial G over 128 rows each -> P2
//  blocks 64..4159 : term1 — 64x256 Theta tile, LDS strip-staged (R2 structure),
//                    bf16 frags converted inline from f32 F_ll (L2-resident).
__global__ __launch_bounds__(256) void fused_kernel(const float* __restrict__ Theta,
                                                    const float* __restrict__ Fll,
                                                    const float* __restrict__ Ful,
                                                    float* __restrict__ P1,
                                                    float* __restrict__ P2) {
  __shared__ float pool[2 * 16 * 260 + 8];  // 33.3 KB, also covers term2's 32 KB
  const int t = threadIdx.x;

  if (blockIdx.x < 64) {
    // ---------------- term2 ----------------
    float(*sll)[64] = (float(*)[64])pool;
    float(*sul)[64] = (float(*)[64])(pool + 4096);
    const int j = t & 63, kq = t >> 6;  // kq uniform per wave -> broadcast reads
    float acc[16];
#pragma unroll
    for (int m = 0; m < 16; ++m) acc[m] = 0.f;

    for (int chunk = 0; chunk < 2; ++chunk) {
      const size_t r0 = (size_t)blockIdx.x * 128 + chunk * 64;
      for (int i = t; i < 1024; i += 256) {  // 64*64 f32 = 1024 float4 per matrix
        ((float4*)sll)[i] = ((const float4*)(Fll + r0 * K))[i];
        ((float4*)sul)[i] = ((const float4*)(Ful + r0 * K))[i];
      }
      __syncthreads();
      for (int r = 0; r < 64; ++r) {
        float fl = sll[r][j];
#pragma unroll
        for (int m = 0; m < 16; ++m) acc[m] += sul[r][kq * 16 + m] * fl;
      }
      __syncthreads();
    }
#pragma unroll
    for (int m = 0; m < 16; ++m)
      P2[(size_t)blockIdx.x * 4096 + (kq * 16 + m) * 64 + j] = acc[m];
    return;
  }

  // ---------------- term1 ----------------
  const int bid = blockIdx.x - 64;
  const int lane = t & 63, wave = t >> 6;
  const int bi = bid >> 5;  // 128 i-tiles
  const int bj = bid & 31;  // 32 j-tiles
  const int i0 = bi * 64;
  const int jc0 = bj * 256;
  const int l15 = lane & 15, lg = lane >> 4;

  float* lds0 = pool;
  float* lds1 = pool + 16 * 260;

  // stage strip s into buffer: wave w loads strip-rows {w, w+4, w+8, w+12},
  // each row = 1 KB fully contiguous (64 lanes x 16 B).
#define STAGE(s, lbuf)                                                              \
  {                                                                                 \
    _Pragma("unroll") for (int q = 0; q < 4; ++q) {                                 \
      int row = wave + 4 * q;                                                       \
      const float* g = Theta + (size_t)(i0 + (s)*16 + row) * N + jc0 + lane * 4;    \
      float* l = (lbuf) + row * 260;                                                \
      __builtin_amdgcn_global_load_lds((glob_u8*)g, (lds_u8*)l, 16, 0, 0);          \
    }                                                                               \
  }

  STAGE(0, lds0);

  // build bf16 fragments inline from f32 F_ll (L2-resident, 2 MB)
  bf16x8 afrag[4][2], bfrag[4][2];
#pragma unroll
  for (int m = 0; m < 4; ++m)
#pragma unroll
    for (int ks = 0; ks < 2; ++ks) {
      const float* ar = Fll + (size_t)(i0 + m * 16 + l15) * K + ks * 32 + lg * 8;
      afrag[m][ks] = pack8(*(const float4*)ar, *(const float4*)(ar + 4));
    }
#pragma unroll
  for (int n = 0; n < 4; ++n)
#pragma unroll
    for (int ks = 0; ks < 2; ++ks) {
      const float* br = Fll + (size_t)(jc0 + wave * 64 + n * 16 + l15) * K + ks * 32 + lg * 8;
      bfrag[n][ks] = pack8(*(const float4*)br, *(const float4*)(br + 4));
    }

  float p = 0.f;
  __syncthreads();
#pragma unroll
  for (int s = 0; s < 4; ++s) {
    float* cur = (s & 1) ? lds1 : lds0;
    if (s < 3) STAGE(s + 1, (s & 1) ? lds0 : lds1);
    f32x4 zero = {0.f, 0.f, 0.f, 0.f};
    f32x4 acc[4] = {zero, zero, zero, zero};
#pragma unroll
    for (int jf = 0; jf < 4; ++jf)
#pragma unroll
      for (int ks = 0; ks < 2; ++ks)
        acc[jf] = __builtin_amdgcn_mfma_f32_16x16x32_bf16(afrag[s][ks], bfrag[jf][ks],
                                                          acc[jf], 0, 0, 0);
#pragma unroll
    for (int jf = 0; jf < 4; ++jf)
#pragma unroll
      for (int r = 0; r < 4; ++r)
        p += acc[jf][r] * cur[(lg * 4 + r) * 260 + wave * 64 + jf * 16 + l15];
    __syncthreads();
  }

#pragma unroll
  for (int off = 32; off > 0; off >>= 1) p += __shfl_down(p, off, 64);
  __shared__ float red[4];
  if (lane == 0) red[wave] = p;
  __syncthreads();
  if (t == 0) P1[bid] = (red[0] + red[1]) + (red[2] + red[3]);
}

// stage2: 64 blocks. Block b sums P1 slice [b*64, +64) and finishes G columns
// kj in [b*64, +64) across the 64 term2 partials, squaring.
__global__ __launch_bounds__(256) void stage2_kernel(const float* __restrict__ P1,
                                                     const float* __restrict__ P2,
                                                     float* __restrict__ R1,
                                                     float* __restrict__ R2) {
  __shared__ float sg[4][64];
  const int t = threadIdx.x, b = blockIdx.x;
  const int l = t & 63, q = t >> 6;
  const int kj = b * 64 + l;
  float gp = 0.f;
  for (int blk = q * 16; blk < q * 16 + 16; ++blk) gp += P2[(size_t)blk * 4096 + kj];
  sg[q][l] = gp;
  float a = (t < 64) ? P1[b * 64 + t] : 0.f;
  __syncthreads();
  if (q == 0) {
    float g = (sg[0][l] + sg[1][l]) + (sg[2][l] + sg[3][l]);
    float r2 = g * g;
    float r1 = a;
#pragma unroll
    for (int off = 32; off > 0; off >>= 1) {
      r2 += __shfl_down(r2, off, 64);
      r1 += __shfl_down(r1, off, 64);
    }
    if (l == 0) {
      R1[b] = r1;
      R2[b] = r2;
    }
  }
}

__global__ void final_kernel(const float* __restrict__ R1, const float* __restrict__ R2,
                             const float* __restrict__ lam, float* __restrict__ out) {
  const int t = threadIdx.x;  // 64 threads
  float r1 = R1[t], r2 = R2[t];
#pragma unroll
  for (int off = 32; off > 0; off >>= 1) {
    r1 += __shfl_down(r1, off, 64);
    r2 += __shfl_down(r2, off, 64);
  }
  if (t == 0) out[0] = r1 + lam[0] * r2;
}

extern "C" void kernel_launch(void* const* d_in, const int* in_sizes, int n_in,
                              void* d_out, int out_size, void* d_ws, size_t ws_size,
                              hipStream_t stream) {
  const float* Fll = (const float*)d_in[0];
  const float* Ful = (const float*)d_in[1];
  const float* Theta = (const float*)d_in[2];
  const float* lam = (const float*)d_in[3];
  float* out = (float*)d_out;

  char* ws = (char*)d_ws;
  float* P1 = (float*)ws;                   // 16 KB
  float* P2 = (float*)(ws + 0x10000u);      // 1 MB
  float* R1 = (float*)(ws + 0x120000u);
  float* R2 = (float*)(ws + 0x120400u);

  fused_kernel<<<4160, 256, 0, stream>>>(Theta, Fll, Ful, P1, P2);
  stage2_kernel<<<64, 256, 0, stream>>>(P1, P2, R1, R2);
  final_kernel<<<1, 64, 0, stream>>>(R1, R2, lam, out);
}

// Round 5
// 87.111 us; speedup vs baseline: 1.0750x; 1.0750x over previous
//
#include <hip/hip_runtime.h>
#include <hip/hip_bf16.h>
#include <stdint.h>

#define N 8192
#define K 64

typedef __attribute__((ext_vector_type(8))) __bf16 bf16x8;
typedef __attribute__((ext_vector_type(4))) float f32x4;
typedef __attribute__((address_space(3))) uint8_t lds_u8;
typedef __attribute__((address_space(1))) const uint8_t glob_u8;

// ws layout:
//   [0, 1MB)               : W0 = F_ll as bf16 (ushort), 8192*64
//   [1MB, 1MB+16KB)        : P1 term1 per-block partials (4096 f32)
//   [1MB+64KB, +4MB)       : P2 term2 per-block partial G (256 * 4096 f32)
//   [0x510000, +256B)      : R1 stage2 partials (64 f32)
//   [0x510400, +256B)      : R2 stage2 partials (64 f32)
//   [0x510800, +4B)        : cnt (last-block counter)

static __device__ __forceinline__ uint32_t f2bf(float f) {
  uint32_t x = __float_as_uint(f);
  return (x + 0x7FFFu + ((x >> 16) & 1u)) >> 16;  // RNE f32->bf16
}

// term2 + bf16 convert fused. 256 blocks, each owns 32 rows.
__global__ __launch_bounds__(256) void term2_kernel(const float* __restrict__ Fll,
                                                    const float* __restrict__ Ful,
                                                    float* __restrict__ P2,
                                                    ushort* __restrict__ W0,
                                                    unsigned* __restrict__ cnt) {
  __shared__ float sll[32][64];
  __shared__ float sul[32][64];
  const int t = threadIdx.x;
  const int j = t & 63, kq = t >> 6;  // kq uniform per wave -> broadcast LDS reads
  const size_t r0 = (size_t)blockIdx.x * 32;

  if (blockIdx.x == 0 && t == 0) *cnt = 0u;  // reset last-block counter each launch

  for (int i = t; i < 512; i += 256) {  // 32*64 f32 = 512 float4 per matrix
    ((float4*)sll)[i] = ((const float4*)(Fll + r0 * K))[i];
    ((float4*)sul)[i] = ((const float4*)(Ful + r0 * K))[i];
  }
  __syncthreads();

  // emit bf16 copy of this block's F_ll rows (flat layout matches global)
  const float* sf = (const float*)sll;
  {
    int f = t * 8;
    uint32_t r[8];
#pragma unroll
    for (int e = 0; e < 8; ++e) r[e] = f2bf(sf[f + e]);
    uint4 o;
    o.x = r[0] | (r[1] << 16);
    o.y = r[2] | (r[3] << 16);
    o.z = r[4] | (r[5] << 16);
    o.w = r[6] | (r[7] << 16);
    *(uint4*)&W0[r0 * K + f] = o;
  }

  float acc[16];
#pragma unroll
  for (int m = 0; m < 16; ++m) acc[m] = 0.f;
  for (int r = 0; r < 32; ++r) {
    float fl = sll[r][j];
#pragma unroll
    for (int m = 0; m < 16; ++m) acc[m] += sul[r][kq * 16 + m] * fl;
  }
#pragma unroll
  for (int m = 0; m < 16; ++m)
    P2[(size_t)blockIdx.x * 4096 + (kq * 16 + m) * 64 + j] = acc[m];
}

// term1: block = 64 x 256 Theta tile, LDS strip-staged via global_load_lds(16B),
// double-buffered with COUNTED vmcnt(4) + raw barriers (T4): prefetch stays in
// flight across the barrier instead of being drained by __syncthreads.
__global__ __launch_bounds__(256) void term1_kernel(const float* __restrict__ Theta,
                                                    const ushort* __restrict__ Fb,
                                                    float* __restrict__ P1) {
  __shared__ float lds[2][16 * 260];
  const int t = threadIdx.x;
  const int lane = t & 63, wave = t >> 6;
  const int bi = blockIdx.x >> 5;  // 128 i-tiles
  const int bj = blockIdx.x & 31;  // 32 j-tiles
  const int i0 = bi * 64;
  const int jc0 = bj * 256;
  const int l15 = lane & 15, lg = lane >> 4;

  // stage strip s: wave w loads strip-rows {w, w+4, w+8, w+12}, 1KB each,
  // exactly 4 VMEM instructions per wave (vmcnt accounting relies on this).
#define STAGE(s, buf)                                                                \
  {                                                                                  \
    _Pragma("unroll") for (int q = 0; q < 4; ++q) {                                  \
      int row = wave + 4 * q;                                                        \
      const float* g = Theta + (size_t)(i0 + (s)*16 + row) * N + jc0 + lane * 4;     \
      float* l = &lds[buf][row * 260];                                               \
      __builtin_amdgcn_global_load_lds((glob_u8*)g, (lds_u8*)l, 16, 0, 0);           \
    }                                                                                \
  }

  STAGE(0, 0);

  bf16x8 afrag[4][2], bfrag[4][2];
#pragma unroll
  for (int m = 0; m < 4; ++m)
#pragma unroll
    for (int ks = 0; ks < 2; ++ks)
      afrag[m][ks] = *(const bf16x8*)&Fb[(size_t)(i0 + m * 16 + l15) * K + ks * 32 + lg * 8];
#pragma unroll
  for (int n = 0; n < 4; ++n)
#pragma unroll
    for (int ks = 0; ks < 2; ++ks)
      bfrag[n][ks] =
          *(const bf16x8*)&Fb[(size_t)(jc0 + wave * 64 + n * 16 + l15) * K + ks * 32 + lg * 8];

  STAGE(1, 1);

  float p = 0.f;
#pragma unroll
  for (int s = 0; s < 4; ++s) {
    // wait for strip s's 4 loads (oldest); keep strip s+1's 4 in flight.
    if (s < 3)
      asm volatile("s_waitcnt vmcnt(4)" ::: "memory");
    else
      asm volatile("s_waitcnt vmcnt(0)" ::: "memory");
    __builtin_amdgcn_s_barrier();  // all waves' strip-s loads landed
    __builtin_amdgcn_sched_barrier(0);

    f32x4 zero = {0.f, 0.f, 0.f, 0.f};
    f32x4 acc[4] = {zero, zero, zero, zero};
#pragma unroll
    for (int jf = 0; jf < 4; ++jf)
#pragma unroll
      for (int ks = 0; ks < 2; ++ks)
        acc[jf] = __builtin_amdgcn_mfma_f32_16x16x32_bf16(afrag[s][ks], bfrag[jf][ks],
                                                          acc[jf], 0, 0, 0);
    const float* cur = &lds[s & 1][0];
#pragma unroll
    for (int jf = 0; jf < 4; ++jf)
#pragma unroll
      for (int r = 0; r < 4; ++r)
        p += acc[jf][r] * cur[(lg * 4 + r) * 260 + wave * 64 + jf * 16 + l15];

    if (s < 3) {
      __builtin_amdgcn_sched_barrier(0);
      __builtin_amdgcn_s_barrier();  // all waves done reading buf[s&1]
      if (s < 2) STAGE(s + 2, s & 1);  // refill the buffer just released
    }
  }

#pragma unroll
  for (int off = 32; off > 0; off >>= 1) p += __shfl_down(p, off, 64);
  __shared__ float red[4];
  if (lane == 0) red[wave] = p;
  __syncthreads();
  if (t == 0) P1[blockIdx.x] = (red[0] + red[1]) + (red[2] + red[3]);
}

// stage2 + final merged (last-block pattern). 64 blocks; block b sums P1 slice
// [b*64,+64) and finishes G cols kj in [b*64,+64) over the 256 term2 partials.
__global__ __launch_bounds__(256) void stage2_kernel(const float* __restrict__ P1,
                                                     const float* __restrict__ P2,
                                                     const float* __restrict__ lam,
                                                     float* __restrict__ out,
                                                     float* __restrict__ R1,
                                                     float* __restrict__ R2,
                                                     unsigned* __restrict__ cnt) {
  __shared__ float sg[4][64];
  __shared__ unsigned is_last;
  const int t = threadIdx.x, b = blockIdx.x;
  const int l = t & 63, q = t >> 6;
  const int kj = b * 64 + l;
  float gp = 0.f;
  for (int blk = q * 64; blk < q * 64 + 64; ++blk) gp += P2[(size_t)blk * 4096 + kj];
  sg[q][l] = gp;
  float a = (t < 64) ? P1[b * 64 + t] : 0.f;
  __syncthreads();
  if (q == 0) {
    float g = (sg[0][l] + sg[1][l]) + (sg[2][l] + sg[3][l]);
    float r2 = g * g;
    float r1 = a;
#pragma unroll
    for (int off = 32; off > 0; off >>= 1) {
      r2 += __shfl_down(r2, off, 64);
      r1 += __shfl_down(r1, off, 64);
    }
    if (l == 0) {
      R1[b] = r1;
      R2[b] = r2;
    }
  }
  if (t == 0) {
    __threadfence();  // publish R1[b]/R2[b] device-wide
    unsigned old = atomicAdd(cnt, 1u);
    __threadfence();  // acquire side for the last block's reads
    is_last = (old == 63u) ? 1u : 0u;
  }
  __syncthreads();
  if (is_last && t < 64) {
    float r1 = R1[t], r2 = R2[t];
#pragma unroll
    for (int off = 32; off > 0; off >>= 1) {
      r1 += __shfl_down(r1, off, 64);
      r2 += __shfl_down(r2, off, 64);
    }
    if (t == 0) out[0] = r1 + lam[0] * r2;
  }
}

extern "C" void kernel_launch(void* const* d_in, const int* in_sizes, int n_in,
                              void* d_out, int out_size, void* d_ws, size_t ws_size,
                              hipStream_t stream) {
  const float* Fll = (const float*)d_in[0];
  const float* Ful = (const float*)d_in[1];
  const float* Theta = (const float*)d_in[2];
  const float* lam = (const float*)d_in[3];
  float* out = (float*)d_out;

  char* ws = (char*)d_ws;
  ushort* W0 = (ushort*)ws;                            // 1 MB bf16 F_ll
  float* P1 = (float*)(ws + (1u << 20));               // 16 KB
  float* P2 = (float*)(ws + (1u << 20) + (1u << 16));  // 4 MB
  float* R1 = (float*)(ws + 0x510000u);
  float* R2 = (float*)(ws + 0x510400u);
  unsigned* cnt = (unsigned*)(ws + 0x510800u);

  term2_kernel<<<256, 256, 0, stream>>>(Fll, Ful, P2, W0, cnt);
  term1_kernel<<<4096, 256, 0, stream>>>(Theta, W0, P1);
  stage2_kernel<<<64, 256, 0, stream>>>(P1, P2, lam, out, R1, R2, cnt);
}

// Round 6
// 66.460 us; speedup vs baseline: 1.4090x; 1.3107x over previous
//
#include <hip/hip_runtime.h>
#include <hip/hip_bf16.h>
#include <stdint.h>

#define N 8192
#define K 64

typedef __attribute__((ext_vector_type(8))) __bf16 bf16x8;
typedef __attribute__((ext_vector_type(4))) float f32x4;
typedef __attribute__((address_space(3))) uint8_t lds_u8;
typedef __attribute__((address_space(1))) const uint8_t glob_u8;

// ws layout (same as R2 + cnt):
//   [0, 1MB)               : W0 = F_ll as bf16 (ushort), 8192*64
//   [1MB, 1MB+16KB)        : P1 term1 per-block partials (4096 f32)
//   [1MB+64KB, +2MB)       : P2 term2 per-block partial G (128 * 4096 f32)
//   [0x310000, +256B)      : R1 stage2 partials (64 f32)
//   [0x310400, +256B)      : R2 stage2 partials (64 f32)
//   [0x310800, +4B)        : cnt (last-block counter)

static __device__ __forceinline__ uint32_t f2bf(float f) {
  uint32_t x = __float_as_uint(f);
  return (x + 0x7FFFu + ((x >> 16) & 1u)) >> 16;  // RNE f32->bf16
}

// term2 + bf16 convert fused (R2-exact, proven). 128 blocks, each owns 64 rows.
__global__ __launch_bounds__(256) void term2_kernel(const float* __restrict__ Fll,
                                                    const float* __restrict__ Ful,
                                                    float* __restrict__ P2,
                                                    ushort* __restrict__ W0,
                                                    unsigned* __restrict__ cnt) {
  __shared__ float sll[64][64];
  __shared__ float sul[64][64];
  const int t = threadIdx.x;
  const int j = t & 63, kq = t >> 6;  // kq uniform per wave -> broadcast LDS reads
  const size_t r0 = (size_t)blockIdx.x * 64;

  if (blockIdx.x == 0 && t == 0) *cnt = 0u;  // reset last-block counter every launch

  for (int i = t; i < 1024; i += 256) {
    ((float4*)sll)[i] = ((const float4*)(Fll + r0 * K))[i];
    ((float4*)sul)[i] = ((const float4*)(Ful + r0 * K))[i];
  }
  __syncthreads();

  const float* sf = (const float*)sll;
#pragma unroll
  for (int h = 0; h < 2; ++h) {
    int f = t * 8 + h * 2048;
    uint32_t r[8];
#pragma unroll
    for (int e = 0; e < 8; ++e) r[e] = f2bf(sf[f + e]);
    uint4 o;
    o.x = r[0] | (r[1] << 16);
    o.y = r[2] | (r[3] << 16);
    o.z = r[4] | (r[5] << 16);
    o.w = r[6] | (r[7] << 16);
    *(uint4*)&W0[r0 * K + f] = o;
  }

  float acc[16];
#pragma unroll
  for (int m = 0; m < 16; ++m) acc[m] = 0.f;
  for (int r = 0; r < 64; ++r) {
    float fl = sll[r][j];
#pragma unroll
    for (int m = 0; m < 16; ++m) acc[m] += sul[r][kq * 16 + m] * fl;
  }
#pragma unroll
  for (int m = 0; m < 16; ++m)
    P2[(size_t)blockIdx.x * 4096 + (kq * 16 + m) * 64 + j] = acc[m];
}

// term1: 64x256 Theta tile; each wave stages ITS OWN 16x64 strip-slice into
// wave-private LDS double buffers. No s_barrier in the K-loop: per-wave
// counted s_waitcnt vmcnt(4) only. lgkmcnt(0) guards buffer refill against
// in-flight ds_reads. One STAGE = 4 global_load_lds (vmcnt accounting: the
// per-iteration STAGE is the only in-loop VMEM, so any compiler reordering
// of the prologue frag loads can only over-wait, never under-wait.
__global__ __launch_bounds__(256) void term1_kernel(const float* __restrict__ Theta,
                                                    const ushort* __restrict__ Fb,
                                                    float* __restrict__ P1) {
  __shared__ float lds[4][2][1024];  // [wave][buf][16 rows x 64 cols] = 32 KB
  const int t = threadIdx.x;
  const int lane = t & 63, wave = t >> 6;
  const int bi = blockIdx.x >> 5;  // 128 i-tiles
  const int bj = blockIdx.x & 31;  // 32 j-tiles
  const int i0 = bi * 64;
  const int jc0 = bj * 256;
  const int l15 = lane & 15, lg = lane >> 4;

  // fragment loads FIRST (so the STAGEs are the newest VMEM ops)
  bf16x8 afrag[4][2], bfrag[4][2];
#pragma unroll
  for (int m = 0; m < 4; ++m)
#pragma unroll
    for (int ks = 0; ks < 2; ++ks)
      afrag[m][ks] = *(const bf16x8*)&Fb[(size_t)(i0 + m * 16 + l15) * K + ks * 32 + lg * 8];
#pragma unroll
  for (int n = 0; n < 4; ++n)
#pragma unroll
    for (int ks = 0; ks < 2; ++ks)
      bfrag[n][ks] =
          *(const bf16x8*)&Fb[(size_t)(jc0 + wave * 64 + n * 16 + l15) * K + ks * 32 + lg * 8];

  // STAGE strip s (rows i0+s*16 .. +15) of this wave's 64-col slice.
  // Instr g covers strip-rows 4g..4g+3; lane l -> row 4g+(l>>4), col 4*(l&15).
  // LDS dest = wave-uniform base + lane*16B (HW requirement), element layout
  // [row][col] row-major 64 floats/row.
#define STAGE(s, buf)                                                                  \
  {                                                                                    \
    _Pragma("unroll") for (int g = 0; g < 4; ++g) {                                    \
      const float* gsrc = Theta + (size_t)(i0 + (s)*16 + g * 4 + lg) * N + jc0 +       \
                          wave * 64 + 4 * l15;                                         \
      float* ldst = &lds[wave][buf][g * 256];                                          \
      __builtin_amdgcn_global_load_lds((glob_u8*)gsrc, (lds_u8*)ldst, 16, 0, 0);       \
    }                                                                                  \
  }

  // NB: in STAGE, lane l must map to row 4g+(l>>4), col 4*(l&15): the HW writes
  // lane l at ldst + l*16B = offset g*256 + 4*l floats = (4g + l>>4)*64 + 4*(l&15). OK.
  // gsrc uses lg = lane>>4 and l15 = lane&15 accordingly.

  STAGE(0, 0);
  STAGE(1, 1);

  float p = 0.f;
#pragma unroll
  for (int s = 0; s < 4; ++s) {
    // wait for strip s's 4 loads (oldest); keep the newest 4 (strip s+1) in flight
    if (s < 3)
      asm volatile("s_waitcnt vmcnt(4)" ::: "memory");
    else
      asm volatile("s_waitcnt vmcnt(0)" ::: "memory");

    f32x4 zero = {0.f, 0.f, 0.f, 0.f};
    f32x4 acc[4] = {zero, zero, zero, zero};
#pragma unroll
    for (int jf = 0; jf < 4; ++jf)
#pragma unroll
      for (int ks = 0; ks < 2; ++ks)
        acc[jf] = __builtin_amdgcn_mfma_f32_16x16x32_bf16(afrag[s][ks], bfrag[jf][ks],
                                                          acc[jf], 0, 0, 0);
    const float* cur = &lds[wave][s & 1][0];
#pragma unroll
    for (int jf = 0; jf < 4; ++jf)
#pragma unroll
      for (int r = 0; r < 4; ++r)
        p += acc[jf][r] * cur[(lg * 4 + r) * 64 + jf * 16 + l15];

    if (s < 2) {
      // all ds_reads of buf (s&1) must complete before the DMA refill lands
      asm volatile("s_waitcnt lgkmcnt(0)" ::: "memory");
      STAGE(s + 2, s & 1);
    }
  }

#pragma unroll
  for (int off = 32; off > 0; off >>= 1) p += __shfl_down(p, off, 64);
  __syncthreads();  // all waves done with their private LDS; reuse it for reduce
  if (lane == 0) lds[0][0][wave] = p;
  __syncthreads();
  if (t == 0)
    P1[blockIdx.x] = (lds[0][0][0] + lds[0][0][1]) + (lds[0][0][2] + lds[0][0][3]);
}

// stage2 + final merged (last-block pattern, proven in R5). 64 blocks; block b
// sums P1 slice [b*64,+64) and finishes G cols kj in [b*64,+64) over 128 partials.
__global__ __launch_bounds__(256) void stage2_kernel(const float* __restrict__ P1,
                                                     const float* __restrict__ P2,
                                                     const float* __restrict__ lam,
                                                     float* __restrict__ out,
                                                     float* __restrict__ R1,
                                                     float* __restrict__ R2,
                                                     unsigned* __restrict__ cnt) {
  __shared__ float sg[4][64];
  __shared__ unsigned is_last;
  const int t = threadIdx.x, b = blockIdx.x;
  const int l = t & 63, q = t >> 6;
  const int kj = b * 64 + l;
  float gp = 0.f;
  for (int blk = q * 32; blk < q * 32 + 32; ++blk) gp += P2[(size_t)blk * 4096 + kj];
  sg[q][l] = gp;
  float a = (t < 64) ? P1[b * 64 + t] : 0.f;
  __syncthreads();
  if (q == 0) {
    float g = (sg[0][l] + sg[1][l]) + (sg[2][l] + sg[3][l]);
    float r2 = g * g;
    float r1 = a;
#pragma unroll
    for (int off = 32; off > 0; off >>= 1) {
      r2 += __shfl_down(r2, off, 64);
      r1 += __shfl_down(r1, off, 64);
    }
    if (l == 0) {
      R1[b] = r1;
      R2[b] = r2;
    }
  }
  if (t == 0) {
    __threadfence();  // publish R1[b]/R2[b]
    unsigned old = atomicAdd(cnt, 1u);
    __threadfence();  // acquire for last block's reads
    is_last = (old == 63u) ? 1u : 0u;
  }
  __syncthreads();
  if (is_last && t < 64) {
    float r1 = R1[t], r2 = R2[t];
#pragma unroll
    for (int off = 32; off > 0; off >>= 1) {
      r1 += __shfl_down(r1, off, 64);
      r2 += __shfl_down(r2, off, 64);
    }
    if (t == 0) out[0] = r1 + lam[0] * r2;
  }
}

extern "C" void kernel_launch(void* const* d_in, const int* in_sizes, int n_in,
                              void* d_out, int out_size, void* d_ws, size_t ws_size,
                              hipStream_t stream) {
  const float* Fll = (const float*)d_in[0];
  const float* Ful = (const float*)d_in[1];
  const float* Theta = (const float*)d_in[2];
  const float* lam = (const float*)d_in[3];
  float* out = (float*)d_out;

  char* ws = (char*)d_ws;
  ushort* W0 = (ushort*)ws;                            // 1 MB bf16 F_ll
  float* P1 = (float*)(ws + (1u << 20));               // 16 KB
  float* P2 = (float*)(ws + (1u << 20) + (1u << 16));  // 2 MB
  float* R1 = (float*)(ws + 0x310000u);
  float* R2 = (float*)(ws + 0x310400u);
  unsigned* cnt = (unsigned*)(ws + 0x310800u);

  term2_kernel<<<128, 256, 0, stream>>>(Fll, Ful, P2, W0, cnt);
  term1_kernel<<<4096, 256, 0, stream>>>(Theta, W0, P1);
  stage2_kernel<<<64, 256, 0, stream>>>(P1, P2, lam, out, R1, R2, cnt);
}